// Round 2
// baseline (1157.694 us; speedup 1.0000x reference)
//
#include <hip/hip_runtime.h>
#include <math.h>

// UnifiedCortexGPT fp32 baseline with hard top-K sparsity exploited.
// B=4096, D=512, C=16, K=204. All fp32.

#define BM 128
#define BN 64
#define BKD 16
#define KSEL 204

__device__ __forceinline__ float gelu_f(float x) {
  // exact (erf) gelu, matches jax.nn.gelu(approximate=False)
  return 0.5f * x * (1.0f + erff(x * 0.70710678118654752f));
}

// ---------------- dense GEMM: C = act(A[M,K] @ B[K,N] + bias) ----------------
// M % 128 == 0, N % 64 == 0, K % 16 == 0 (all dense shapes satisfy this)
template <int ACT>
__global__ __launch_bounds__(256) void gemm_k(
    const float* __restrict__ A, const float* __restrict__ Bm,
    const float* __restrict__ bias, float* __restrict__ C,
    int M, int N, int K) {
  __shared__ float As[BKD][BM + 4];
  __shared__ float Bs[BKD][BN + 4];
  const int tid = threadIdx.x;
  const int tx = tid & 15;   // col group (4 cols)
  const int ty = tid >> 4;   // row group (8 rows)
  const int row0 = blockIdx.y * BM;
  const int col0 = blockIdx.x * BN;
  const int ak = tid & 15;   // k for A load
  const int ar = tid >> 4;   // base row for A load
  const int bn = tid & 63;   // n for B load
  const int bk0 = tid >> 6;  // base k for B load

  float acc[8][4];
#pragma unroll
  for (int i = 0; i < 8; i++)
#pragma unroll
    for (int j = 0; j < 4; j++) acc[i][j] = 0.f;

  for (int k0 = 0; k0 < K; k0 += BKD) {
#pragma unroll
    for (int i = 0; i < 8; i++) {
      int r = row0 + ar + 16 * i;
      As[ak][ar + 16 * i] = A[(size_t)r * K + k0 + ak];
    }
#pragma unroll
    for (int i = 0; i < 4; i++) {
      int kk = bk0 + 4 * i;
      Bs[kk][bn] = Bm[(size_t)(k0 + kk) * N + col0 + bn];
    }
    __syncthreads();
#pragma unroll
    for (int kk = 0; kk < BKD; kk++) {
      float a[8], b[4];
#pragma unroll
      for (int i = 0; i < 8; i++) a[i] = As[kk][ty * 8 + i];
#pragma unroll
      for (int j = 0; j < 4; j++) b[j] = Bs[kk][tx * 4 + j];
#pragma unroll
      for (int i = 0; i < 8; i++)
#pragma unroll
        for (int j = 0; j < 4; j++) acc[i][j] = fmaf(a[i], b[j], acc[i][j]);
    }
    __syncthreads();
  }
#pragma unroll
  for (int i = 0; i < 8; i++) {
    int r = row0 + ty * 8 + i;
#pragma unroll
    for (int j = 0; j < 4; j++) {
      int cc = col0 + tx * 4 + j;
      float v = acc[i][j] + bias[cc];
      if (ACT == 1) v = gelu_f(v);
      C[(size_t)r * N + cc] = v;
    }
  }
}

// ------------- gate GEMM: A = concat(fast,slow), epilogue computes h -------------
__global__ __launch_bounds__(256) void gemm_gate_k(
    const float* __restrict__ fastb, const float* __restrict__ slowb,
    const float* __restrict__ gw, const float* __restrict__ gb,
    const float* __restrict__ x, float* __restrict__ h) {
  const int N = 512, K = 1024;
  __shared__ float As[BKD][BM + 4];
  __shared__ float Bs[BKD][BN + 4];
  const int tid = threadIdx.x;
  const int tx = tid & 15, ty = tid >> 4;
  const int row0 = blockIdx.y * BM, col0 = blockIdx.x * BN;
  const int ak = tid & 15, ar = tid >> 4, bn = tid & 63, bk0 = tid >> 6;

  float acc[8][4];
#pragma unroll
  for (int i = 0; i < 8; i++)
#pragma unroll
    for (int j = 0; j < 4; j++) acc[i][j] = 0.f;

  for (int k0 = 0; k0 < K; k0 += BKD) {
    int k = k0 + ak;
    const float* Asrc = (k < 512) ? (fastb + k) : (slowb + (k - 512));
#pragma unroll
    for (int i = 0; i < 8; i++) {
      int r = row0 + ar + 16 * i;
      As[ak][ar + 16 * i] = Asrc[(size_t)r * 512];
    }
#pragma unroll
    for (int i = 0; i < 4; i++) {
      int kk = bk0 + 4 * i;
      Bs[kk][bn] = gw[(size_t)(k0 + kk) * N + col0 + bn];
    }
    __syncthreads();
#pragma unroll
    for (int kk = 0; kk < BKD; kk++) {
      float a[8], b[4];
#pragma unroll
      for (int i = 0; i < 8; i++) a[i] = As[kk][ty * 8 + i];
#pragma unroll
      for (int j = 0; j < 4; j++) b[j] = Bs[kk][tx * 4 + j];
#pragma unroll
      for (int i = 0; i < 8; i++)
#pragma unroll
        for (int j = 0; j < 4; j++) acc[i][j] = fmaf(a[i], b[j], acc[i][j]);
    }
    __syncthreads();
  }
#pragma unroll
  for (int i = 0; i < 8; i++) {
    int r = row0 + ty * 8 + i;
#pragma unroll
    for (int j = 0; j < 4; j++) {
      int cc = col0 + tx * 4 + j;
      float gate = 1.f / (1.f + expf(-(acc[i][j] + gb[cc])));
      size_t idx = (size_t)r * 512 + cc;
      float f = fastb[idx], sl = slowb[idx], xv = x[idx];
      h[idx] = gate * (0.91f * f + 0.09f * sl) + (1.f - gate) * xv;
    }
  }
}

// ------------- gathered column GEMM 1: p1[c] = gelu(h[sel] @ cw1[c] + cb1[c]) -------------
__global__ __launch_bounds__(256) void gemm_col1_k(
    const float* __restrict__ h, const float* __restrict__ cw1,
    const float* __restrict__ cb1, float* __restrict__ p1,
    const int* __restrict__ selidx) {
  const int N = 1024, K = 512;
  const int c = blockIdx.z;
  const float* Bm = cw1 + (size_t)c * K * N;
  const float* bias = cb1 + (size_t)c * N;
  float* Cc = p1 + (size_t)c * 256 * N;
  const int* rmap = selidx + c * 256;

  __shared__ float As[BKD][BM + 4];
  __shared__ float Bs[BKD][BN + 4];
  const int tid = threadIdx.x;
  const int tx = tid & 15, ty = tid >> 4;
  const int row0 = blockIdx.y * BM, col0 = blockIdx.x * BN;
  const int ak = tid & 15, ar = tid >> 4, bn = tid & 63, bk0 = tid >> 6;

  int grow[8];
#pragma unroll
  for (int i = 0; i < 8; i++) {
    int r = row0 + ar + 16 * i;
    grow[i] = (r < KSEL) ? rmap[r] : -1;
  }

  float acc[8][4];
#pragma unroll
  for (int i = 0; i < 8; i++)
#pragma unroll
    for (int j = 0; j < 4; j++) acc[i][j] = 0.f;

  for (int k0 = 0; k0 < K; k0 += BKD) {
#pragma unroll
    for (int i = 0; i < 8; i++) {
      As[ak][ar + 16 * i] =
          (grow[i] >= 0) ? h[(size_t)grow[i] * K + k0 + ak] : 0.f;
    }
#pragma unroll
    for (int i = 0; i < 4; i++) {
      int kk = bk0 + 4 * i;
      Bs[kk][bn] = Bm[(size_t)(k0 + kk) * N + col0 + bn];
    }
    __syncthreads();
#pragma unroll
    for (int kk = 0; kk < BKD; kk++) {
      float a[8], b[4];
#pragma unroll
      for (int i = 0; i < 8; i++) a[i] = As[kk][ty * 8 + i];
#pragma unroll
      for (int j = 0; j < 4; j++) b[j] = Bs[kk][tx * 4 + j];
#pragma unroll
      for (int i = 0; i < 8; i++)
#pragma unroll
        for (int j = 0; j < 4; j++) acc[i][j] = fmaf(a[i], b[j], acc[i][j]);
    }
    __syncthreads();
  }
#pragma unroll
  for (int i = 0; i < 8; i++) {
    int r = row0 + ty * 8 + i;
    if (r >= KSEL) continue;
#pragma unroll
    for (int j = 0; j < 4; j++) {
      int cc = col0 + tx * 4 + j;
      Cc[(size_t)r * N + cc] = gelu_f(acc[i][j] + bias[cc]);
    }
  }
}

// ------------- column GEMM 2: p2[c] = gelu(p1[c] @ cw2[c] + cb2[c]) -------------
__global__ __launch_bounds__(256) void gemm_col2_k(
    const float* __restrict__ p1, const float* __restrict__ cw2,
    const float* __restrict__ cb2, float* __restrict__ p2) {
  const int N = 512, K = 1024;
  const int c = blockIdx.z;
  const float* A = p1 + (size_t)c * 256 * K;
  const float* Bm = cw2 + (size_t)c * K * N;
  const float* bias = cb2 + (size_t)c * N;
  float* Cc = p2 + (size_t)c * 256 * N;

  __shared__ float As[BKD][BM + 4];
  __shared__ float Bs[BKD][BN + 4];
  const int tid = threadIdx.x;
  const int tx = tid & 15, ty = tid >> 4;
  const int row0 = blockIdx.y * BM, col0 = blockIdx.x * BN;
  const int ak = tid & 15, ar = tid >> 4, bn = tid & 63, bk0 = tid >> 6;

  float acc[8][4];
#pragma unroll
  for (int i = 0; i < 8; i++)
#pragma unroll
    for (int j = 0; j < 4; j++) acc[i][j] = 0.f;

  for (int k0 = 0; k0 < K; k0 += BKD) {
#pragma unroll
    for (int i = 0; i < 8; i++) {
      int r = row0 + ar + 16 * i;
      As[ak][ar + 16 * i] = (r < KSEL) ? A[(size_t)r * K + k0 + ak] : 0.f;
    }
#pragma unroll
    for (int i = 0; i < 4; i++) {
      int kk = bk0 + 4 * i;
      Bs[kk][bn] = Bm[(size_t)(k0 + kk) * N + col0 + bn];
    }
    __syncthreads();
#pragma unroll
    for (int kk = 0; kk < BKD; kk++) {
      float a[8], b[4];
#pragma unroll
      for (int i = 0; i < 8; i++) a[i] = As[kk][ty * 8 + i];
#pragma unroll
      for (int j = 0; j < 4; j++) b[j] = Bs[kk][tx * 4 + j];
#pragma unroll
      for (int i = 0; i < 8; i++)
#pragma unroll
        for (int j = 0; j < 4; j++) acc[i][j] = fmaf(a[i], b[j], acc[i][j]);
    }
    __syncthreads();
  }
#pragma unroll
  for (int i = 0; i < 8; i++) {
    int r = row0 + ty * 8 + i;
    if (r >= KSEL) continue;
#pragma unroll
    for (int j = 0; j < 4; j++) {
      int cc = col0 + tx * 4 + j;
      Cc[(size_t)r * N + cc] = gelu_f(acc[i][j] + bias[cc]);
    }
  }
}

// ---------------- LayerNorm W=512, shared gamma/beta (slow path) ----------------
__global__ __launch_bounds__(256) void ln512_k(
    const float* __restrict__ in, const float* __restrict__ g,
    const float* __restrict__ b, float* __restrict__ out, int nrows) {
  int wave = threadIdx.x >> 6, lane = threadIdx.x & 63;
  int row = blockIdx.x * 4 + wave;
  if (row >= nrows) return;
  const float4* r4 = (const float4*)(in + (size_t)row * 512);
  float4 v0 = r4[lane * 2], v1 = r4[lane * 2 + 1];
  float s = v0.x + v0.y + v0.z + v0.w + v1.x + v1.y + v1.z + v1.w;
#pragma unroll
  for (int o = 32; o; o >>= 1) s += __shfl_xor(s, o);
  float mean = s * (1.0f / 512.0f);
  float q = 0.f;
  {
    float dx;
    dx = v0.x - mean; q += dx * dx;  dx = v0.y - mean; q += dx * dx;
    dx = v0.z - mean; q += dx * dx;  dx = v0.w - mean; q += dx * dx;
    dx = v1.x - mean; q += dx * dx;  dx = v1.y - mean; q += dx * dx;
    dx = v1.z - mean; q += dx * dx;  dx = v1.w - mean; q += dx * dx;
  }
#pragma unroll
  for (int o = 32; o; o >>= 1) q += __shfl_xor(q, o);
  float rstd = rsqrtf(q * (1.0f / 512.0f) + 1e-5f);
  const float4* g4 = (const float4*)g;
  const float4* b4 = (const float4*)b;
  float4 gg0 = g4[lane * 2], gg1 = g4[lane * 2 + 1];
  float4 bb0 = b4[lane * 2], bb1 = b4[lane * 2 + 1];
  float4 o0, o1;
  o0.x = (v0.x - mean) * rstd * gg0.x + bb0.x;
  o0.y = (v0.y - mean) * rstd * gg0.y + bb0.y;
  o0.z = (v0.z - mean) * rstd * gg0.z + bb0.z;
  o0.w = (v0.w - mean) * rstd * gg0.w + bb0.w;
  o1.x = (v1.x - mean) * rstd * gg1.x + bb1.x;
  o1.y = (v1.y - mean) * rstd * gg1.y + bb1.y;
  o1.z = (v1.z - mean) * rstd * gg1.z + bb1.z;
  o1.w = (v1.w - mean) * rstd * gg1.w + bb1.w;
  float4* w4 = (float4*)(out + (size_t)row * 512);
  w4[lane * 2] = o0;
  w4[lane * 2 + 1] = o1;
}

// ---------------- LayerNorm W=1024, per-column gamma/beta, in-place on p1 ----------------
__global__ __launch_bounds__(256) void ln1024_k(
    float* __restrict__ p1, const float* __restrict__ g,
    const float* __restrict__ b) {
  int wave = threadIdx.x >> 6, lane = threadIdx.x & 63;
  int row = blockIdx.x * 4 + wave;
  int c = blockIdx.y;
  if (row >= KSEL) return;
  float4* r4 = (float4*)(p1 + ((size_t)c * 256 + row) * 1024);
  float4 v[4];
#pragma unroll
  for (int i = 0; i < 4; i++) v[i] = r4[lane * 4 + i];
  float s = 0.f;
#pragma unroll
  for (int i = 0; i < 4; i++) s += v[i].x + v[i].y + v[i].z + v[i].w;
#pragma unroll
  for (int o = 32; o; o >>= 1) s += __shfl_xor(s, o);
  float mean = s * (1.0f / 1024.0f);
  float q = 0.f;
#pragma unroll
  for (int i = 0; i < 4; i++) {
    float dx = v[i].x - mean, dy = v[i].y - mean;
    float dz = v[i].z - mean, dw = v[i].w - mean;
    q += dx * dx + dy * dy + dz * dz + dw * dw;
  }
#pragma unroll
  for (int o = 32; o; o >>= 1) q += __shfl_xor(q, o);
  float rstd = rsqrtf(q * (1.0f / 1024.0f) + 1e-5f);
  const float4* g4 = (const float4*)(g + (size_t)c * 1024);
  const float4* b4 = (const float4*)(b + (size_t)c * 1024);
#pragma unroll
  for (int i = 0; i < 4; i++) {
    float4 gg = g4[lane * 4 + i], bb = b4[lane * 4 + i];
    float4 o4;
    o4.x = (v[i].x - mean) * rstd * gg.x + bb.x;
    o4.y = (v[i].y - mean) * rstd * gg.y + bb.y;
    o4.z = (v[i].z - mean) * rstd * gg.z + bb.z;
    o4.w = (v[i].w - mean) * rstd * gg.w + bb.w;
    r4[lane * 4 + i] = o4;
  }
}

// ---------- LayerNorm W=512 on p2, per-column gamma/beta, scatter-add to accum ----------
__global__ __launch_bounds__(256) void ln512s_k(
    const float* __restrict__ p2, const float* __restrict__ g,
    const float* __restrict__ b, const int* __restrict__ selidx,
    float* __restrict__ accum) {
  int wave = threadIdx.x >> 6, lane = threadIdx.x & 63;
  int row = blockIdx.x * 4 + wave;
  int c = blockIdx.y;
  if (row >= KSEL) return;
  const float4* r4 = (const float4*)(p2 + ((size_t)c * 256 + row) * 512);
  float4 v0 = r4[lane * 2], v1 = r4[lane * 2 + 1];
  float s = v0.x + v0.y + v0.z + v0.w + v1.x + v1.y + v1.z + v1.w;
#pragma unroll
  for (int o = 32; o; o >>= 1) s += __shfl_xor(s, o);
  float mean = s * (1.0f / 512.0f);
  float q = 0.f;
  {
    float dx;
    dx = v0.x - mean; q += dx * dx;  dx = v0.y - mean; q += dx * dx;
    dx = v0.z - mean; q += dx * dx;  dx = v0.w - mean; q += dx * dx;
    dx = v1.x - mean; q += dx * dx;  dx = v1.y - mean; q += dx * dx;
    dx = v1.z - mean; q += dx * dx;  dx = v1.w - mean; q += dx * dx;
  }
#pragma unroll
  for (int o = 32; o; o >>= 1) q += __shfl_xor(q, o);
  float rstd = rsqrtf(q * (1.0f / 512.0f) + 1e-5f);
  const float4* g4 = (const float4*)(g + (size_t)c * 512);
  const float4* b4 = (const float4*)(b + (size_t)c * 512);
  float4 gg0 = g4[lane * 2], gg1 = g4[lane * 2 + 1];
  float4 bb0 = b4[lane * 2], bb1 = b4[lane * 2 + 1];
  int bg = selidx[c * 256 + row];
  float* dst = accum + (size_t)bg * 512 + lane * 8;
  atomicAdd(&dst[0], (v0.x - mean) * rstd * gg0.x + bb0.x);
  atomicAdd(&dst[1], (v0.y - mean) * rstd * gg0.y + bb0.y);
  atomicAdd(&dst[2], (v0.z - mean) * rstd * gg0.z + bb0.z);
  atomicAdd(&dst[3], (v0.w - mean) * rstd * gg0.w + bb0.w);
  atomicAdd(&dst[4], (v1.x - mean) * rstd * gg1.x + bb1.x);
  atomicAdd(&dst[5], (v1.y - mean) * rstd * gg1.y + bb1.y);
  atomicAdd(&dst[6], (v1.z - mean) * rstd * gg1.z + bb1.z);
  atomicAdd(&dst[7], (v1.w - mean) * rstd * gg1.w + bb1.w);
}

// ---------------- scores[c][b] = h[b] . colg_w[c] + colg_b[c] ----------------
__global__ __launch_bounds__(256) void scores_k(
    const float* __restrict__ h, const float* __restrict__ cw,
    const float* __restrict__ cb, float* __restrict__ scores) {
  int wave = threadIdx.x >> 6, lane = threadIdx.x & 63;
  int b = blockIdx.x * 4 + wave;
  const float4* hr = (const float4*)(h + (size_t)b * 512);
  float4 h0 = hr[lane * 2], h1 = hr[lane * 2 + 1];
#pragma unroll
  for (int c = 0; c < 16; c++) {
    const float4* w4 = (const float4*)(cw + (size_t)c * 512);
    float4 w0 = w4[lane * 2], w1 = w4[lane * 2 + 1];
    float acc = h0.x * w0.x + h0.y * w0.y + h0.z * w0.z + h0.w * w0.w +
                h1.x * w1.x + h1.y * w1.y + h1.z * w1.z + h1.w * w1.w;
#pragma unroll
    for (int o = 32; o; o >>= 1) acc += __shfl_xor(acc, o);
    if (lane == 0) scores[c * 4096 + b] = acc + cb[c];
  }
}

// ---------------- exact top-K selection (ties by lower index, like lax.top_k) ----------------
__global__ __launch_bounds__(256) void select_k(
    const float* __restrict__ scores, int* __restrict__ selcnt,
    int* __restrict__ selidx) {
  __shared__ float s[4096];
  const int c = blockIdx.y;
  const int t = threadIdx.x;
  const float* sc = scores + c * 4096;
#pragma unroll
  for (int i = 0; i < 16; i++) s[t + 256 * i] = sc[t + 256 * i];
  __syncthreads();
  const int b = blockIdx.x * 256 + t;
  const float v = s[b];
  int rank = 0;
  for (int j = 0; j < 4096; j += 4) {
    float s0 = s[j], s1 = s[j + 1], s2 = s[j + 2], s3 = s[j + 3];
    rank += (s0 > v) + (s1 > v) + (s2 > v) + (s3 > v);
    rank += ((s0 == v) && (j + 0 < b)) + ((s1 == v) && (j + 1 < b)) +
            ((s2 == v) && (j + 2 < b)) + ((s3 == v) && (j + 3 < b));
  }
  if (rank < KSEL) {
    int pos = atomicAdd(&selcnt[c], 1);
    selidx[c * 256 + pos] = b;
  }
}

// ---------------- out = h + (RES/C) * accum ----------------
__global__ __launch_bounds__(256) void final_k(
    const float* __restrict__ h, const float* __restrict__ acc,
    float* __restrict__ out) {
  int i = blockIdx.x * 256 + threadIdx.x;
  float4 hv = ((const float4*)h)[i];
  float4 av = ((const float4*)acc)[i];
  float4 o;
  o.x = hv.x + 0.00625f * av.x;
  o.y = hv.y + 0.00625f * av.y;
  o.z = hv.z + 0.00625f * av.z;
  o.w = hv.w + 0.00625f * av.w;
  ((float4*)out)[i] = o;
}

extern "C" void kernel_launch(void* const* d_in, const int* in_sizes, int n_in,
                              void* d_out, int out_size, void* d_ws,
                              size_t ws_size, hipStream_t stream) {
  const float* x = (const float*)d_in[0];
  const float* fw1 = (const float*)d_in[1];
  const float* fb1 = (const float*)d_in[2];
  const float* fw2 = (const float*)d_in[3];
  const float* fb2 = (const float*)d_in[4];
  const float* sw1 = (const float*)d_in[5];
  const float* sb1 = (const float*)d_in[6];
  const float* sg = (const float*)d_in[7];
  const float* sbeta = (const float*)d_in[8];
  const float* sw2 = (const float*)d_in[9];
  const float* sb2 = (const float*)d_in[10];
  const float* gw = (const float*)d_in[11];
  const float* gb = (const float*)d_in[12];
  const float* cw1 = (const float*)d_in[13];
  const float* cb1 = (const float*)d_in[14];
  const float* cg1 = (const float*)d_in[15];
  const float* cbe1 = (const float*)d_in[16];
  const float* cw2 = (const float*)d_in[17];
  const float* cb2 = (const float*)d_in[18];
  const float* cg2 = (const float*)d_in[19];
  const float* cbe2 = (const float*)d_in[20];
  const float* cgw = (const float*)d_in[21];
  const float* cgb = (const float*)d_in[22];

  float* ws = (float*)d_ws;
  float* y1 = ws;                    // 4,194,304 floats  (reused as p1)
  float* fastb = ws + 4194304;       // 2,097,152
  float* s1 = ws + 6291456;          // 2,097,152        (reused as p2)
  float* s1n = ws + 8388608;         // 2,097,152
  float* slowb = ws + 10485760;      // 2,097,152
  float* h = ws + 12582912;          // 2,097,152
  float* accum = ws + 14680064;      // 2,097,152
  float* scores = ws + 16777216;     // 65,536
  int* selidx = (int*)(ws + 16842752);  // 4096 ints
  int* selcnt = selidx + 4096;          // 16 ints
  float* p1 = y1;
  float* p2 = s1;

  hipMemsetAsync(accum, 0, 2097152 * sizeof(float), stream);
  hipMemsetAsync(selcnt, 0, 16 * sizeof(int), stream);

  dim3 blk(256);
  // fast path: y1 = gelu(x @ fw1 + fb1); fast = gelu(y1 @ fw2 + fb2)
  gemm_k<1><<<dim3(16, 32), blk, 0, stream>>>(x, fw1, fb1, y1, 4096, 1024, 512);
  gemm_k<1><<<dim3(8, 32), blk, 0, stream>>>(y1, fw2, fb2, fastb, 4096, 512, 1024);
  // slow path: s1 = gelu(x @ sw1 + sb1); s1n = LN(s1); slow = gelu(s1n @ sw2 + sb2)
  gemm_k<1><<<dim3(8, 32), blk, 0, stream>>>(x, sw1, sb1, s1, 4096, 512, 512);
  ln512_k<<<1024, blk, 0, stream>>>(s1, sg, sbeta, s1n, 4096);
  gemm_k<1><<<dim3(8, 32), blk, 0, stream>>>(s1n, sw2, sb2, slowb, 4096, 512, 512);
  // gate + mix + residual blend -> h
  gemm_gate_k<<<dim3(8, 32), blk, 0, stream>>>(fastb, slowb, gw, gb, x, h);
  // column gate scores + exact top-K selection
  scores_k<<<1024, blk, 0, stream>>>(h, cgw, cgb, scores);
  select_k<<<dim3(16, 16), blk, 0, stream>>>(scores, selcnt, selidx);
  // sparse column compute (only selected rows)
  gemm_col1_k<<<dim3(16, 2, 16), blk, 0, stream>>>(h, cw1, cb1, p1, selidx);
  ln1024_k<<<dim3(51, 16), blk, 0, stream>>>(p1, cg1, cbe1);
  gemm_col2_k<<<dim3(8, 2, 16), blk, 0, stream>>>(p1, cw2, cb2, p2);
  ln512s_k<<<dim3(51, 16), blk, 0, stream>>>(p2, cg2, cbe2, selidx, accum);
  // out = h + 0.1/16 * accum
  final_k<<<2048, blk, 0, stream>>>(h, accum, (float*)d_out);
}

// Round 3
// 498.923 us; speedup vs baseline: 2.3204x; 2.3204x over previous
//
#include <hip/hip_runtime.h>
#include <math.h>

// UnifiedCortexGPT — bf16 MFMA version. B=4096, D=512, C=16, K_sel=204.
// All GEMMs: 128x64 tile, BK=64, 4 waves (2x2), mfma_f32_16x16x32_bf16,
// global_load_lds(16B) staging with XOR slot swizzle (rule 21: inverse-swizzled
// global source + swizzled LDS read).

#define KSEL 204

typedef unsigned short u16;
typedef __attribute__((ext_vector_type(8))) short bf16x8;
typedef __attribute__((ext_vector_type(4))) float f32x4;
typedef __attribute__((ext_vector_type(8))) unsigned short u16x8;

__device__ __forceinline__ float gelu_f(float x) {
  return 0.5f * x * (1.0f + erff(x * 0.70710678118654752f));
}
__device__ __forceinline__ u16 f2b(float f) {  // RNE fp32->bf16
  unsigned u = __float_as_uint(f);
  u += 0x7fff + ((u >> 16) & 1);
  return (u16)(u >> 16);
}
__device__ __forceinline__ float b2f(u16 b) {
  return __uint_as_float(((unsigned)b) << 16);
}

#define GLOAD_LDS(gsrc, ldst)                                                  \
  __builtin_amdgcn_global_load_lds(                                            \
      (const __attribute__((address_space(1))) void*)(gsrc),                   \
      (__attribute__((address_space(3))) void*)(ldst), 16, 0, 0)

// ---------------- transpose-convert: src[K][N] f32 -> dst[N][K] bf16 ----------
__global__ __launch_bounds__(256) void transpose_b_k(
    const float* __restrict__ src, u16* __restrict__ dst, int K, int N) {
  __shared__ float t[32][33];
  const size_t mz = (size_t)blockIdx.z * K * N;
  int k0 = blockIdx.y * 32, n0 = blockIdx.x * 32;
  int r = threadIdx.x >> 5, c = threadIdx.x & 31;
#pragma unroll
  for (int i = 0; i < 4; i++)
    t[r + 8 * i][c] = src[mz + (size_t)(k0 + r + 8 * i) * N + n0 + c];
  __syncthreads();
#pragma unroll
  for (int i = 0; i < 4; i++)
    dst[mz + (size_t)(n0 + r + 8 * i) * K + k0 + c] = f2b(t[c][r + 8 * i]);
}

// ---------------- elementwise f32 -> bf16 ----------------
__global__ __launch_bounds__(256) void cvt_k(const float* __restrict__ src,
                                             u16* __restrict__ dst, int n4) {
  int i = blockIdx.x * 256 + threadIdx.x;
  if (i < n4) {
    float4 v = ((const float4*)src)[i];
    ushort4 o;
    o.x = f2b(v.x); o.y = f2b(v.y); o.z = f2b(v.z); o.w = f2b(v.w);
    ((ushort4*)dst)[i] = o;
  }
}

// ================= MFMA GEMM template =================
// A [M][K] bf16 (K contig), Bt [N][K] bf16 (K contig), tile 128(M)x64(N), BK=64.
// 256 thr = 4 waves 2x2: wave(wm,wn) owns rows wm*64+[0,64), cols wn*32+[0,32).
// EPI: 0 = gelu -> bf16 out (ldOutB)    1 = gelu -> f32 out (stride N)
//      2 = gate: sigmoid(acc+bias); h = g*mix + (1-g)*x -> f32 + bf16
//      3 = gelu -> f32 out, rows >= Mvalid masked
template <int EPI>
__global__ __launch_bounds__(256) void mgemm_k(
    const u16* __restrict__ A, const u16* __restrict__ Bt,
    const float* __restrict__ bias, float* __restrict__ outF,
    u16* __restrict__ outB, int ldOutB, const float* __restrict__ xres,
    int M, int N, int K, int Mvalid,
    long szA, long szB, long szBias, long szOutF) {
  __shared__ __align__(16) u16 As[128 * 64];  // 16KB
  __shared__ __align__(16) u16 Bs[64 * 64];   // 8KB
  const int tid = threadIdx.x;
  const int wid = tid >> 6, lane = tid & 63;
  const int wm = wid & 1, wn = wid >> 1;
  const int row0 = blockIdx.y * 128, col0 = blockIdx.x * 64;
  const size_t z = blockIdx.z;
  const u16* Ap = A + z * szA;
  const u16* Bp = Bt + z * szB;
  const float* biasp = bias + z * szBias;

  // staging decomposition: thread t -> row t>>3, linear slot t&7,
  // source slot (t&7)^((t>>3)&7)  (XOR involution, matches read swizzle)
  const int srow = tid >> 3;
  const int sslot = (tid & 7) ^ (srow & 7);

  f32x4 acc[4][2];
#pragma unroll
  for (int mi = 0; mi < 4; mi++)
#pragma unroll
    for (int ni = 0; ni < 2; ni++) acc[mi][ni] = (f32x4){0.f, 0.f, 0.f, 0.f};

  const int q = lane >> 4, rl = lane & 15;

  for (int k0 = 0; k0 < K; k0 += 64) {
#pragma unroll
    for (int i = 0; i < 4; i++) {
      const u16* src = Ap + (size_t)(row0 + i * 32 + srow) * K + k0 + sslot * 8;
      GLOAD_LDS(src, (char*)As + i * 4096 + wid * 1024);
    }
#pragma unroll
    for (int i = 0; i < 2; i++) {
      const u16* src = Bp + (size_t)(col0 + i * 32 + srow) * K + k0 + sslot * 8;
      GLOAD_LDS(src, (char*)Bs + i * 4096 + wid * 1024);
    }
    __syncthreads();
#pragma unroll
    for (int h = 0; h < 2; h++) {
      bf16x8 af[4], bfr[2];
#pragma unroll
      for (int mi = 0; mi < 4; mi++) {
        int row = wm * 64 + mi * 16 + rl;
        int slot = (h * 4 + q) ^ (row & 7);
        af[mi] = *(const bf16x8*)((const char*)As + row * 128 + slot * 16);
      }
#pragma unroll
      for (int ni = 0; ni < 2; ni++) {
        int n = wn * 32 + ni * 16 + rl;
        int slot = (h * 4 + q) ^ (n & 7);
        bfr[ni] = *(const bf16x8*)((const char*)Bs + n * 128 + slot * 16);
      }
#pragma unroll
      for (int mi = 0; mi < 4; mi++)
#pragma unroll
        for (int ni = 0; ni < 2; ni++)
          acc[mi][ni] = __builtin_amdgcn_mfma_f32_16x16x32_bf16(
              af[mi], bfr[ni], acc[mi][ni], 0, 0, 0);
    }
    __syncthreads();
  }

  // epilogue: C frag layout col = lane&15, row = (lane>>4)*4 + r
#pragma unroll
  for (int ni = 0; ni < 2; ni++) {
    const int col = col0 + wn * 32 + ni * 16 + rl;
    const float bv = biasp[col];
#pragma unroll
    for (int mi = 0; mi < 4; mi++) {
#pragma unroll
      for (int r = 0; r < 4; r++) {
        const int row = row0 + wm * 64 + mi * 16 + q * 4 + r;
        float v = acc[mi][ni][r] + bv;
        if (EPI == 0) {
          outB[(size_t)row * ldOutB + col] = f2b(gelu_f(v));
        } else if (EPI == 1) {
          (outF + z * szOutF)[(size_t)row * N + col] = gelu_f(v);
        } else if (EPI == 2) {
          float g = 1.f / (1.f + expf(-v));
          float fa = b2f(Ap[(size_t)row * 1024 + col]);
          float sl = b2f(Ap[(size_t)row * 1024 + 512 + col]);
          float xv = xres[(size_t)row * 512 + col];
          float hv = g * (0.91f * fa + 0.09f * sl) + (1.f - g) * xv;
          outF[(size_t)row * 512 + col] = hv;
          outB[(size_t)row * 512 + col] = f2b(hv);
        } else {  // EPI == 3
          if (row < Mvalid)
            (outF + z * szOutF)[(size_t)row * N + col] = gelu_f(v);
        }
      }
    }
  }
}

// ---------- column GEMM 1 with row gather: p1bf[c] = gelu_bf16(h[sel] @ cw1T[c]) ----------
__global__ __launch_bounds__(256) void mgemm_col1_k(
    const u16* __restrict__ hbf, const u16* __restrict__ cw1T,
    const float* __restrict__ cb1, u16* __restrict__ p1bf,
    const int* __restrict__ selidx) {
  const int N = 1024, K = 512;
  __shared__ __align__(16) u16 As[128 * 64];
  __shared__ __align__(16) u16 Bs[64 * 64];
  const int tid = threadIdx.x;
  const int wid = tid >> 6, lane = tid & 63;
  const int wm = wid & 1, wn = wid >> 1;
  const int row0 = blockIdx.y * 128, col0 = blockIdx.x * 64;
  const int c = blockIdx.z;
  const u16* Bp = cw1T + (size_t)c * N * K;
  const float* biasp = cb1 + (size_t)c * N;
  u16* outp = p1bf + (size_t)c * 256 * N;
  const int* rmap = selidx + c * 256;

  const int srow = tid >> 3;
  const int sslot = (tid & 7) ^ (srow & 7);
  int gr[4];
#pragma unroll
  for (int i = 0; i < 4; i++) {
    int rli = row0 + i * 32 + srow;
    gr[i] = (rli < KSEL) ? rmap[rli] : 0;
  }

  f32x4 acc[4][2];
#pragma unroll
  for (int mi = 0; mi < 4; mi++)
#pragma unroll
    for (int ni = 0; ni < 2; ni++) acc[mi][ni] = (f32x4){0.f, 0.f, 0.f, 0.f};
  const int q = lane >> 4, rl = lane & 15;

  for (int k0 = 0; k0 < K; k0 += 64) {
#pragma unroll
    for (int i = 0; i < 4; i++) {
      const u16* src = hbf + (size_t)gr[i] * 512 + k0 + sslot * 8;
      GLOAD_LDS(src, (char*)As + i * 4096 + wid * 1024);
    }
#pragma unroll
    for (int i = 0; i < 2; i++) {
      const u16* src = Bp + (size_t)(col0 + i * 32 + srow) * K + k0 + sslot * 8;
      GLOAD_LDS(src, (char*)Bs + i * 4096 + wid * 1024);
    }
    __syncthreads();
#pragma unroll
    for (int h = 0; h < 2; h++) {
      bf16x8 af[4], bfr[2];
#pragma unroll
      for (int mi = 0; mi < 4; mi++) {
        int row = wm * 64 + mi * 16 + rl;
        int slot = (h * 4 + q) ^ (row & 7);
        af[mi] = *(const bf16x8*)((const char*)As + row * 128 + slot * 16);
      }
#pragma unroll
      for (int ni = 0; ni < 2; ni++) {
        int n = wn * 32 + ni * 16 + rl;
        int slot = (h * 4 + q) ^ (n & 7);
        bfr[ni] = *(const bf16x8*)((const char*)Bs + n * 128 + slot * 16);
      }
#pragma unroll
      for (int mi = 0; mi < 4; mi++)
#pragma unroll
        for (int ni = 0; ni < 2; ni++)
          acc[mi][ni] = __builtin_amdgcn_mfma_f32_16x16x32_bf16(
              af[mi], bfr[ni], acc[mi][ni], 0, 0, 0);
    }
    __syncthreads();
  }

#pragma unroll
  for (int ni = 0; ni < 2; ni++) {
    const int col = col0 + wn * 32 + ni * 16 + rl;
    const float bv = biasp[col];
#pragma unroll
    for (int mi = 0; mi < 4; mi++) {
#pragma unroll
      for (int r = 0; r < 4; r++) {
        const int row = row0 + wm * 64 + mi * 16 + q * 4 + r;
        if (row < KSEL)
          outp[(size_t)row * N + col] = f2b(gelu_f(acc[mi][ni][r] + bv));
      }
    }
  }
}

// ---------------- LayerNorm 512 f32 -> bf16 (slow path) ----------------
__global__ __launch_bounds__(256) void ln512bf_k(
    const float* __restrict__ in, const float* __restrict__ g,
    const float* __restrict__ b, u16* __restrict__ out, int nrows) {
  int wave = threadIdx.x >> 6, lane = threadIdx.x & 63;
  int row = blockIdx.x * 4 + wave;
  if (row >= nrows) return;
  const float4* r4 = (const float4*)(in + (size_t)row * 512);
  float4 v0 = r4[lane * 2], v1 = r4[lane * 2 + 1];
  float s = v0.x + v0.y + v0.z + v0.w + v1.x + v1.y + v1.z + v1.w;
#pragma unroll
  for (int o = 32; o; o >>= 1) s += __shfl_xor(s, o);
  float mean = s * (1.0f / 512.0f);
  float qv = 0.f;
  {
    float dx;
    dx = v0.x - mean; qv += dx * dx;  dx = v0.y - mean; qv += dx * dx;
    dx = v0.z - mean; qv += dx * dx;  dx = v0.w - mean; qv += dx * dx;
    dx = v1.x - mean; qv += dx * dx;  dx = v1.y - mean; qv += dx * dx;
    dx = v1.z - mean; qv += dx * dx;  dx = v1.w - mean; qv += dx * dx;
  }
#pragma unroll
  for (int o = 32; o; o >>= 1) qv += __shfl_xor(qv, o);
  float rstd = rsqrtf(qv * (1.0f / 512.0f) + 1e-5f);
  const float4* g4 = (const float4*)g;
  const float4* b4 = (const float4*)b;
  float4 gg0 = g4[lane * 2], gg1 = g4[lane * 2 + 1];
  float4 bb0 = b4[lane * 2], bb1 = b4[lane * 2 + 1];
  u16x8 o8;
  o8[0] = f2b((v0.x - mean) * rstd * gg0.x + bb0.x);
  o8[1] = f2b((v0.y - mean) * rstd * gg0.y + bb0.y);
  o8[2] = f2b((v0.z - mean) * rstd * gg0.z + bb0.z);
  o8[3] = f2b((v0.w - mean) * rstd * gg0.w + bb0.w);
  o8[4] = f2b((v1.x - mean) * rstd * gg1.x + bb1.x);
  o8[5] = f2b((v1.y - mean) * rstd * gg1.y + bb1.y);
  o8[6] = f2b((v1.z - mean) * rstd * gg1.z + bb1.z);
  o8[7] = f2b((v1.w - mean) * rstd * gg1.w + bb1.w);
  *(u16x8*)(out + (size_t)row * 512 + lane * 8) = o8;
}

// ---------------- LayerNorm 1024 in-place on bf16 p1, per-column g/b ----------------
__global__ __launch_bounds__(256) void ln1024bf_k(
    u16* __restrict__ p, const float* __restrict__ g,
    const float* __restrict__ b) {
  int wave = threadIdx.x >> 6, lane = threadIdx.x & 63;
  int row = blockIdx.x * 4 + wave;
  int c = blockIdx.y;
  if (row >= KSEL) return;
  u16* rp = p + ((size_t)c * 256 + row) * 1024 + lane * 16;
  u16x8 a0 = *(const u16x8*)rp;
  u16x8 a1 = *(const u16x8*)(rp + 8);
  float f[16];
#pragma unroll
  for (int j = 0; j < 8; j++) { f[j] = b2f(a0[j]); f[8 + j] = b2f(a1[j]); }
  float s = 0.f;
#pragma unroll
  for (int j = 0; j < 16; j++) s += f[j];
#pragma unroll
  for (int o = 32; o; o >>= 1) s += __shfl_xor(s, o);
  float mean = s * (1.0f / 1024.0f);
  float qv = 0.f;
#pragma unroll
  for (int j = 0; j < 16; j++) { float d = f[j] - mean; qv += d * d; }
#pragma unroll
  for (int o = 32; o; o >>= 1) qv += __shfl_xor(qv, o);
  float rstd = rsqrtf(qv * (1.0f / 1024.0f) + 1e-5f);
  const float* gp = g + (size_t)c * 1024 + lane * 16;
  const float* bp = b + (size_t)c * 1024 + lane * 16;
  u16x8 o0, o1;
#pragma unroll
  for (int j = 0; j < 8; j++)
    o0[j] = f2b((f[j] - mean) * rstd * gp[j] + bp[j]);
#pragma unroll
  for (int j = 0; j < 8; j++)
    o1[j] = f2b((f[8 + j] - mean) * rstd * gp[8 + j] + bp[8 + j]);
  *(u16x8*)rp = o0;
  *(u16x8*)(rp + 8) = o1;
}

// ---------- LayerNorm 512 on p2 f32, per-column g/b, scatter-add to accum ----------
__global__ __launch_bounds__(256) void ln512s_k(
    const float* __restrict__ p2, const float* __restrict__ g,
    const float* __restrict__ b, const int* __restrict__ selidx,
    float* __restrict__ accum) {
  int wave = threadIdx.x >> 6, lane = threadIdx.x & 63;
  int row = blockIdx.x * 4 + wave;
  int c = blockIdx.y;
  if (row >= KSEL) return;
  const float4* r4 = (const float4*)(p2 + ((size_t)c * 256 + row) * 512);
  float4 v0 = r4[lane * 2], v1 = r4[lane * 2 + 1];
  float s = v0.x + v0.y + v0.z + v0.w + v1.x + v1.y + v1.z + v1.w;
#pragma unroll
  for (int o = 32; o; o >>= 1) s += __shfl_xor(s, o);
  float mean = s * (1.0f / 512.0f);
  float qv = 0.f;
  {
    float dx;
    dx = v0.x - mean; qv += dx * dx;  dx = v0.y - mean; qv += dx * dx;
    dx = v0.z - mean; qv += dx * dx;  dx = v0.w - mean; qv += dx * dx;
    dx = v1.x - mean; qv += dx * dx;  dx = v1.y - mean; qv += dx * dx;
    dx = v1.z - mean; qv += dx * dx;  dx = v1.w - mean; qv += dx * dx;
  }
#pragma unroll
  for (int o = 32; o; o >>= 1) qv += __shfl_xor(qv, o);
  float rstd = rsqrtf(qv * (1.0f / 512.0f) + 1e-5f);
  const float4* g4 = (const float4*)(g + (size_t)c * 512);
  const float4* b4 = (const float4*)(b + (size_t)c * 512);
  float4 gg0 = g4[lane * 2], gg1 = g4[lane * 2 + 1];
  float4 bb0 = b4[lane * 2], bb1 = b4[lane * 2 + 1];
  int bg = selidx[c * 256 + row];
  float* dst = accum + (size_t)bg * 512 + lane * 8;
  atomicAdd(&dst[0], (v0.x - mean) * rstd * gg0.x + bb0.x);
  atomicAdd(&dst[1], (v0.y - mean) * rstd * gg0.y + bb0.y);
  atomicAdd(&dst[2], (v0.z - mean) * rstd * gg0.z + bb0.z);
  atomicAdd(&dst[3], (v0.w - mean) * rstd * gg0.w + bb0.w);
  atomicAdd(&dst[4], (v1.x - mean) * rstd * gg1.x + bb1.x);
  atomicAdd(&dst[5], (v1.y - mean) * rstd * gg1.y + bb1.y);
  atomicAdd(&dst[6], (v1.z - mean) * rstd * gg1.z + bb1.z);
  atomicAdd(&dst[7], (v1.w - mean) * rstd * gg1.w + bb1.w);
}

// ---------------- scores + exact top-K selection (unchanged) ----------------
__global__ __launch_bounds__(256) void scores_k(
    const float* __restrict__ h, const float* __restrict__ cw,
    const float* __restrict__ cb, float* __restrict__ scores) {
  int wave = threadIdx.x >> 6, lane = threadIdx.x & 63;
  int b = blockIdx.x * 4 + wave;
  const float4* hr = (const float4*)(h + (size_t)b * 512);
  float4 h0 = hr[lane * 2], h1 = hr[lane * 2 + 1];
#pragma unroll
  for (int c = 0; c < 16; c++) {
    const float4* w4 = (const float4*)(cw + (size_t)c * 512);
    float4 w0 = w4[lane * 2], w1 = w4[lane * 2 + 1];
    float acc = h0.x * w0.x + h0.y * w0.y + h0.z * w0.z + h0.w * w0.w +
                h1.x * w1.x + h1.y * w1.y + h1.z * w1.z + h1.w * w1.w;
#pragma unroll
    for (int o = 32; o; o >>= 1) acc += __shfl_xor(acc, o);
    if (lane == 0) scores[c * 4096 + b] = acc + cb[c];
  }
}

__global__ __launch_bounds__(256) void select_k(
    const float* __restrict__ scores, int* __restrict__ selcnt,
    int* __restrict__ selidx) {
  __shared__ float s[4096];
  const int c = blockIdx.y;
  const int t = threadIdx.x;
  const float* sc = scores + c * 4096;
#pragma unroll
  for (int i = 0; i < 16; i++) s[t + 256 * i] = sc[t + 256 * i];
  __syncthreads();
  const int b = blockIdx.x * 256 + t;
  const float v = s[b];
  int rank = 0;
  for (int j = 0; j < 4096; j += 4) {
    float s0 = s[j], s1 = s[j + 1], s2 = s[j + 2], s3 = s[j + 3];
    rank += (s0 > v) + (s1 > v) + (s2 > v) + (s3 > v);
    rank += ((s0 == v) && (j + 0 < b)) + ((s1 == v) && (j + 1 < b)) +
            ((s2 == v) && (j + 2 < b)) + ((s3 == v) && (j + 3 < b));
  }
  if (rank < KSEL) {
    int pos = atomicAdd(&selcnt[c], 1);
    selidx[c * 256 + pos] = b;
  }
}

// ---------------- out = h + 0.1/16 * accum ----------------
__global__ __launch_bounds__(256) void final_k(
    const float* __restrict__ h, const float* __restrict__ acc,
    float* __restrict__ out) {
  int i = blockIdx.x * 256 + threadIdx.x;
  float4 hv = ((const float4*)h)[i];
  float4 av = ((const float4*)acc)[i];
  float4 o;
  o.x = hv.x + 0.00625f * av.x;
  o.y = hv.y + 0.00625f * av.y;
  o.z = hv.z + 0.00625f * av.z;
  o.w = hv.w + 0.00625f * av.w;
  ((float4*)out)[i] = o;
}

extern "C" void kernel_launch(void* const* d_in, const int* in_sizes, int n_in,
                              void* d_out, int out_size, void* d_ws,
                              size_t ws_size, hipStream_t stream) {
  const float* x = (const float*)d_in[0];
  const float* fw1 = (const float*)d_in[1];
  const float* fb1 = (const float*)d_in[2];
  const float* fw2 = (const float*)d_in[3];
  const float* fb2 = (const float*)d_in[4];
  const float* sw1 = (const float*)d_in[5];
  const float* sb1 = (const float*)d_in[6];
  const float* sg = (const float*)d_in[7];
  const float* sbeta = (const float*)d_in[8];
  const float* sw2 = (const float*)d_in[9];
  const float* sb2 = (const float*)d_in[10];
  const float* gw = (const float*)d_in[11];
  const float* gb = (const float*)d_in[12];
  const float* cw1 = (const float*)d_in[13];
  const float* cb1 = (const float*)d_in[14];
  const float* cg1 = (const float*)d_in[15];
  const float* cbe1 = (const float*)d_in[16];
  const float* cw2 = (const float*)d_in[17];
  const float* cb2 = (const float*)d_in[18];
  const float* cg2 = (const float*)d_in[19];
  const float* cbe2 = (const float*)d_in[20];
  const float* cgw = (const float*)d_in[21];
  const float* cgb = (const float*)d_in[22];

  char* ws = (char*)d_ws;
  // byte offsets (all 256-aligned)
  u16* cw1T  = (u16*)(ws + 0);           // 16 MB  [16][1024][512]
  u16* cw2T  = (u16*)(ws + 16777216);    // 16 MB  [16][512][1024]
  u16* fw1T  = (u16*)(ws + 33554432);    // 1 MB   [1024][512]
  u16* fw2T  = (u16*)(ws + 34603008);    // 1 MB   [512][1024]
  u16* sw1T  = (u16*)(ws + 35651584);    // 512 KB [512][512]
  u16* sw2T  = (u16*)(ws + 36175872);    // 512 KB
  u16* gwT   = (u16*)(ws + 36700160);    // 1 MB   [512][1024]
  u16* xbf   = (u16*)(ws + 37748736);    // 4 MB   [4096][512]
  u16* s1nbf = (u16*)(ws + 41943040);    // 4 MB
  u16* y1bf  = (u16*)(ws + 46137344);    // 8 MB   [4096][1024]
  float* s1f = (float*)(ws + 54525952);  // 8 MB   [4096][512]
  u16* hcat  = (u16*)(ws + 62914560);    // 8 MB   [4096][1024] fast|slow
  float* hF  = (float*)(ws + 71303168);  // 8 MB
  u16* hbf   = (u16*)(ws + 79691776);    // 4 MB
  float* scores = (float*)(ws + 83886080);   // 256 KB
  int* selidx = (int*)(ws + 84148224);       // 16 KB
  int* selcnt = (int*)(ws + 84164608);       // 64 B
  // overlays (liveness-checked):
  float* accum = (float*)(ws + 37748736);  // over xbf+s1nbf (dead after G4); memset after G5
  u16* p1bf    = (u16*)(ws + 46137344);    // over y1bf (dead after G2)
  float* p2    = (float*)(ws + 54525952);  // over s1f (dead after LN512)

  dim3 blk(256);
  hipMemsetAsync(selcnt, 0, 64, stream);
  // weight transposes + x convert
  cvt_k<<<2048, blk, 0, stream>>>(x, xbf, 524288);
  transpose_b_k<<<dim3(32, 16, 1), blk, 0, stream>>>(fw1, fw1T, 512, 1024);
  transpose_b_k<<<dim3(16, 32, 1), blk, 0, stream>>>(fw2, fw2T, 1024, 512);
  transpose_b_k<<<dim3(16, 16, 1), blk, 0, stream>>>(sw1, sw1T, 512, 512);
  transpose_b_k<<<dim3(16, 16, 1), blk, 0, stream>>>(sw2, sw2T, 512, 512);
  transpose_b_k<<<dim3(16, 32, 1), blk, 0, stream>>>(gw, gwT, 1024, 512);
  transpose_b_k<<<dim3(32, 16, 16), blk, 0, stream>>>(cw1, cw1T, 512, 1024);
  transpose_b_k<<<dim3(16, 32, 16), blk, 0, stream>>>(cw2, cw2T, 1024, 512);

  // G1: y1 = gelu(x @ fw1)            [4096,1024] bf16
  mgemm_k<0><<<dim3(16, 32, 1), blk, 0, stream>>>(
      xbf, fw1T, fb1, nullptr, y1bf, 1024, nullptr, 4096, 1024, 512, 4096, 0, 0, 0, 0);
  // G2: fast = gelu(y1 @ fw2) -> hcat[:, :512] bf16
  mgemm_k<0><<<dim3(8, 32, 1), blk, 0, stream>>>(
      y1bf, fw2T, fb2, nullptr, hcat, 1024, nullptr, 4096, 512, 1024, 4096, 0, 0, 0, 0);
  // G3: s1 = gelu(x @ sw1)            f32
  mgemm_k<1><<<dim3(8, 32, 1), blk, 0, stream>>>(
      xbf, sw1T, sb1, s1f, nullptr, 0, nullptr, 4096, 512, 512, 4096, 0, 0, 0, 0);
  ln512bf_k<<<1024, blk, 0, stream>>>(s1f, sg, sbeta, s1nbf, 4096);
  // G4: slow = gelu(s1n @ sw2) -> hcat[:, 512:] bf16
  mgemm_k<0><<<dim3(8, 32, 1), blk, 0, stream>>>(
      s1nbf, sw2T, sb2, nullptr, hcat + 512, 1024, nullptr, 4096, 512, 512, 4096, 0, 0, 0, 0);
  // G5: gate + mix + blend -> hF f32, hbf bf16
  mgemm_k<2><<<dim3(8, 32, 1), blk, 0, stream>>>(
      hcat, gwT, gb, hF, hbf, 512, x, 4096, 512, 1024, 4096, 0, 0, 0, 0);
  hipMemsetAsync(accum, 0, 8388608, stream);  // accum overlay now free
  // scores + exact top-K
  scores_k<<<1024, blk, 0, stream>>>(hF, cgw, cgb, scores);
  select_k<<<dim3(16, 16), blk, 0, stream>>>(scores, selcnt, selidx);
  // columns (sparse rows only)
  mgemm_col1_k<<<dim3(16, 2, 16), blk, 0, stream>>>(hbf, cw1T, cb1, p1bf, selidx);
  ln1024bf_k<<<dim3(51, 16), blk, 0, stream>>>(p1bf, cg1, cbe1);
  mgemm_k<3><<<dim3(8, 2, 16), blk, 0, stream>>>(
      p1bf, cw2T, cb2, p2, nullptr, 0, nullptr, 256, 512, 1024, KSEL,
      256L * 1024, 512L * 1024, 512, 256L * 512);
  ln512s_k<<<dim3(51, 16), blk, 0, stream>>>(p2, cg2, cbe2, selidx, accum);
  final_k<<<2048, blk, 0, stream>>>(hF, accum, (float*)d_out);
}